// Round 7
// baseline (598.451 us; speedup 1.0000x reference)
//
#include <hip/hip_runtime.h>
#include <math.h>

// GCN forward: 3x GCNConv (128->4->4->2) + classifier (2->4).
// 2D-tiled aggregation: edges partitioned once into (dst-tile 2048 x src-tile
// 2048) buckets; packed word = dl<<11 | sl. Aggregation block holds dst
// accumulator AND current src window of hs in LDS -> random accesses are all
// LDS ops (beats the per-CU L1 divergent-gather wall observed in r4-r6:
// ~14 cyc/edge invariant under occupancy/MLP changes). Global traffic is
// streaming-only. Zero global atomics.

#define CHUNK  8192
#define DTBITS 11
#define DT     2048
#define MAXBK  2432   // >= ND*NW (= 49*49 = 2401 for n = 100000)

// Per-chunk histogram over (dtile,stile) buckets. hb layout: [g][NBK].
__global__ void k_hist(const int* __restrict__ src, const int* __restrict__ dst,
                       int* __restrict__ hb, int NW, int NBK, int e) {
    __shared__ int hist[MAXBK];
    int g = blockIdx.x;
    for (int b = threadIdx.x; b < NBK; b += 256) hist[b] = 0;
    __syncthreads();
    int i0 = g * CHUNK, i1 = min(i0 + CHUNK, e);
    for (int i = i0 + threadIdx.x; i < i1; i += 256) {
        int bk = (dst[i] >> DTBITS) * NW + (src[i] >> DTBITS);
        atomicAdd(&hist[bk], 1);
    }
    __syncthreads();
    for (int b = threadIdx.x; b < NBK; b += 256)
        hb[(size_t)g * NBK + b] = hist[b];
}

// Per-bucket exclusive scan over chunks (block per bucket; strided column
// reads are L2-resident). btot[b] = bucket total.
__global__ void k_scanA(int* __restrict__ hb, int* __restrict__ btot,
                        int NBK, int G) {
    __shared__ int part[256];
    int b = blockIdx.x, t = threadIdx.x;
    int C = (G + 255) / 256;
    int lo = t * C, hi = min(lo + C, G);
    int s = 0;
    for (int i = lo; i < hi; i++) s += hb[(size_t)i * NBK + b];
    part[t] = s;
    __syncthreads();
#pragma unroll
    for (int off = 1; off < 256; off <<= 1) {
        int u = (t >= off) ? part[t - off] : 0;
        __syncthreads();
        part[t] += u;
        __syncthreads();
    }
    int run = part[t] - s;
    for (int i = lo; i < hi; i++) {
        int v = hb[(size_t)i * NBK + b];
        hb[(size_t)i * NBK + b] = run;
        run += v;
    }
    if (t == 255) btot[b] = part[255];
}

// Exclusive scan of NBK bucket totals -> bstart (single block, chunked).
__global__ void k_scanB(const int* __restrict__ btot, int* __restrict__ bstart,
                        int NBK, int e) {
    __shared__ int part[512];
    int t = threadIdx.x;
    int C = (NBK + 511) / 512;
    int lo = t * C, hi = min(lo + C, NBK);
    int s = 0;
    for (int i = lo; i < hi; i++) s += btot[i];
    part[t] = s;
    __syncthreads();
#pragma unroll
    for (int off = 1; off < 512; off <<= 1) {
        int u = (t >= off) ? part[t - off] : 0;
        __syncthreads();
        part[t] += u;
        __syncthreads();
    }
    int run = part[t] - s;
    for (int i = lo; i < hi; i++) {
        bstart[i] = run;
        run += btot[i];
    }
    if (t == 511) bstart[NBK] = e;
}

// Partition edges into (dtile,stile) buckets. packed = dl<<11 | sl.
__global__ void k_part(const int* __restrict__ src, const int* __restrict__ dst,
                       const int* __restrict__ hb, const int* __restrict__ bstart,
                       int* __restrict__ packed, int NW, int NBK, int e) {
    __shared__ int cur[MAXBK];
    int g = blockIdx.x;
    for (int b = threadIdx.x; b < NBK; b += 256)
        cur[b] = hb[(size_t)g * NBK + b] + bstart[b];
    __syncthreads();
    int i0 = g * CHUNK, i1 = min(i0 + CHUNK, e);
    for (int i = i0 + threadIdx.x; i < i1; i += 256) {
        int d = dst[i], s = src[i];
        int bk = (d >> DTBITS) * NW + (s >> DTBITS);
        int pos = atomicAdd(&cur[bk], 1);
        packed[pos] = ((d & (DT - 1)) << DTBITS) | (s & (DT - 1));
    }
}

// Degree: block = (dtile, wgroup); counts dst-local over its contiguous
// edge range (bucket ids for a dtile are contiguous). Partial int counts.
__global__ void k_degt(const int* __restrict__ bstart, const int* __restrict__ packed,
                       int* __restrict__ pdeg, int NW, int NWG) {
    __shared__ int cnt[DT];
    int blk = blockIdx.x;
    int d = blk / NWG, wg = blk - d * NWG;
    int tid = threadIdx.x;
    for (int k = tid; k < DT; k += 256) cnt[k] = 0;
    __syncthreads();
    int wlo = wg * NW / NWG, whi = (wg + 1) * NW / NWG;
    int lo = bstart[d * NW + wlo], hi = bstart[d * NW + whi];
    for (int j = lo + tid; j < hi; j += 256)
        atomicAdd(&cnt[packed[j] >> DTBITS], 1);
    __syncthreads();
    int* P = pdeg + (size_t)blk * DT;
    for (int k = tid; k < DT; k += 256) P[k] = cnt[k];
}

__global__ void k_dinvc(const int* __restrict__ pdeg, float* __restrict__ dinv,
                        int n, int NWG) {
    int d = blockIdx.x >> 3, sl = blockIdx.x & 7;
    int idx = sl * 256 + threadIdx.x;
    int node = (d << DTBITS) + idx;
    if (node >= n) return;
    const int* P = pdeg + ((size_t)d * NWG) * DT + idx;
    int c = 0;
    for (int wg = 0; wg < NWG; wg++) c += P[(size_t)wg * DT];
    dinv[node] = 1.0f / sqrtf((float)(c + 1));
}

// Layer 1 GEMV: one wave per node. hs = (x @ W1) * dinv.
__global__ void k_mm1(const float* __restrict__ x, const float* __restrict__ W,
                      const float* __restrict__ dinv, float* __restrict__ hs, int n) {
    int gid = blockIdx.x * blockDim.x + threadIdx.x;
    int node = gid >> 6;
    int lane = threadIdx.x & 63;
    if (node >= n) return;
    const float2 xv = *reinterpret_cast<const float2*>(x + (size_t)node * 128 + lane * 2);
    const float4 w0 = *reinterpret_cast<const float4*>(W + (lane * 2) * 4);
    const float4 w1 = *reinterpret_cast<const float4*>(W + (lane * 2 + 1) * 4);
    float a0 = xv.x * w0.x + xv.y * w1.x;
    float a1 = xv.x * w0.y + xv.y * w1.y;
    float a2 = xv.x * w0.z + xv.y * w1.z;
    float a3 = xv.x * w0.w + xv.y * w1.w;
#pragma unroll
    for (int m = 32; m >= 1; m >>= 1) {
        a0 += __shfl_xor(a0, m);
        a1 += __shfl_xor(a1, m);
        a2 += __shfl_xor(a2, m);
        a3 += __shfl_xor(a3, m);
    }
    if (lane == 0) {
        float di = dinv[node];
        *reinterpret_cast<float4*>(hs + (size_t)node * 4) =
            make_float4(a0 * di, a1 * di, a2 * di, a3 * di);
    }
}

// Tiled aggregate, 4-wide: block = (dtile, wgroup). For each stile in the
// group: load hs window into LDS (coalesced), then process bucket edges with
// LDS-only random accesses. Partial [4][2048] per block.
__global__ void k_tile4(const int* __restrict__ bstart, const int* __restrict__ packed,
                        const float* __restrict__ hs, float* __restrict__ partial,
                        int n, int NW, int NWG) {
    __shared__ float win[DT * 4];   // 32 KB
    __shared__ float agg[4 * DT];   // 32 KB, plane-major [c][dl]
    int blk = blockIdx.x;
    int d = blk / NWG, wg = blk - d * NWG;
    int tid = threadIdx.x;
    for (int k = tid; k < 4 * DT; k += 256) agg[k] = 0.0f;
    int wlo = wg * NW / NWG, whi = (wg + 1) * NW / NWG;
    for (int w = wlo; w < whi; w++) {
        __syncthreads();  // previous window fully consumed
        int base = w << DTBITS;
        int cnt = min(DT, n - base);
        for (int t = tid; t < cnt; t += 256)
            *reinterpret_cast<float4*>(&win[t * 4]) =
                *reinterpret_cast<const float4*>(hs + (size_t)(base + t) * 4);
        __syncthreads();
        int bk = d * NW + w;
        int lo = bstart[bk], hi = bstart[bk + 1];
        for (int j = lo + tid; j < hi; j += 256) {
            int wd = packed[j];
            int sl = wd & (DT - 1);
            int dl = wd >> DTBITS;
            float4 v = *reinterpret_cast<const float4*>(&win[sl * 4]);
            atomicAdd(&agg[dl], v.x);
            atomicAdd(&agg[DT + dl], v.y);
            atomicAdd(&agg[2 * DT + dl], v.z);
            atomicAdd(&agg[3 * DT + dl], v.w);
        }
    }
    __syncthreads();
    float* P = partial + (size_t)blk * (4 * DT);
    for (int k = tid; k < 4 * DT; k += 256) P[k] = agg[k];
}

// Tiled aggregate, 2-wide.
__global__ void k_tile2(const int* __restrict__ bstart, const int* __restrict__ packed,
                        const float* __restrict__ hs, float* __restrict__ partial,
                        int n, int NW, int NWG) {
    __shared__ float win[DT * 2];   // 16 KB
    __shared__ float agg[2 * DT];   // 16 KB
    int blk = blockIdx.x;
    int d = blk / NWG, wg = blk - d * NWG;
    int tid = threadIdx.x;
    for (int k = tid; k < 2 * DT; k += 256) agg[k] = 0.0f;
    int wlo = wg * NW / NWG, whi = (wg + 1) * NW / NWG;
    for (int w = wlo; w < whi; w++) {
        __syncthreads();
        int base = w << DTBITS;
        int cnt = min(DT, n - base);
        for (int t = tid; t < cnt; t += 256)
            *reinterpret_cast<float2*>(&win[t * 2]) =
                *reinterpret_cast<const float2*>(hs + (size_t)(base + t) * 2);
        __syncthreads();
        int bk = d * NW + w;
        int lo = bstart[bk], hi = bstart[bk + 1];
        for (int j = lo + tid; j < hi; j += 256) {
            int wd = packed[j];
            int sl = wd & (DT - 1);
            int dl = wd >> DTBITS;
            float2 v = *reinterpret_cast<const float2*>(&win[sl * 2]);
            atomicAdd(&agg[dl], v.x);
            atomicAdd(&agg[DT + dl], v.y);
        }
    }
    __syncthreads();
    float* P = partial + (size_t)blk * (2 * DT);
    for (int k = tid; k < 2 * DT; k += 256) P[k] = agg[k];
}

// Combine partials + finalize: h = tanh((agg+hs)*dinv + b); hsn = (h@Wn)*dinv.
template <int FOUT>
__global__ void k_comb4(const float* __restrict__ partial, const float* __restrict__ hs,
                        const float* __restrict__ dinv, const float* __restrict__ b_,
                        const float* __restrict__ Wn, float* __restrict__ hsn,
                        int n, int NWG) {
    int d = blockIdx.x >> 3, sl = blockIdx.x & 7;
    int idx = sl * 256 + threadIdx.x;
    int node = (d << DTBITS) + idx;
    if (node >= n) return;
    const float* P = partial + ((size_t)d * NWG) * (4 * DT) + idx;
    float a0 = 0.f, a1 = 0.f, a2 = 0.f, a3 = 0.f;
    for (int wg = 0; wg < NWG; wg++) {
        const float* q = P + (size_t)wg * (4 * DT);
        a0 += q[0]; a1 += q[DT]; a2 += q[2 * DT]; a3 += q[3 * DT];
    }
    float4 sv = *reinterpret_cast<const float4*>(hs + (size_t)node * 4);
    float di = dinv[node];
    float h0 = tanhf((a0 + sv.x) * di + b_[0]);
    float h1 = tanhf((a1 + sv.y) * di + b_[1]);
    float h2 = tanhf((a2 + sv.z) * di + b_[2]);
    float h3 = tanhf((a3 + sv.w) * di + b_[3]);
    float o[FOUT];
#pragma unroll
    for (int j = 0; j < FOUT; j++) {
        o[j] = (h0 * Wn[0 * FOUT + j] + h1 * Wn[1 * FOUT + j] +
                h2 * Wn[2 * FOUT + j] + h3 * Wn[3 * FOUT + j]) * di;
    }
    if constexpr (FOUT == 4) {
        *reinterpret_cast<float4*>(hsn + (size_t)node * 4) =
            make_float4(o[0], o[1], o[2], o[3]);
    } else {
        *reinterpret_cast<float2*>(hsn + (size_t)node * 2) = make_float2(o[0], o[1]);
    }
}

// Final combine: h3 = tanh(...) -> hout; out = h3@Wc + bc.
__global__ void k_comb3(const float* __restrict__ partial, const float* __restrict__ hs,
                        const float* __restrict__ dinv, const float* __restrict__ b3,
                        const float* __restrict__ Wc, const float* __restrict__ bc,
                        float* __restrict__ out, float* __restrict__ hout,
                        int n, int NWG) {
    int d = blockIdx.x >> 3, sl = blockIdx.x & 7;
    int idx = sl * 256 + threadIdx.x;
    int node = (d << DTBITS) + idx;
    if (node >= n) return;
    const float* P = partial + ((size_t)d * NWG) * (2 * DT) + idx;
    float a0 = 0.f, a1 = 0.f;
    for (int wg = 0; wg < NWG; wg++) {
        const float* q = P + (size_t)wg * (2 * DT);
        a0 += q[0]; a1 += q[DT];
    }
    float2 sv = *reinterpret_cast<const float2*>(hs + (size_t)node * 2);
    float di = dinv[node];
    float h0 = tanhf((a0 + sv.x) * di + b3[0]);
    float h1 = tanhf((a1 + sv.y) * di + b3[1]);
    *reinterpret_cast<float2*>(hout + (size_t)node * 2) = make_float2(h0, h1);
    float4 o;
    o.x = h0 * Wc[0] + h1 * Wc[4] + bc[0];
    o.y = h0 * Wc[1] + h1 * Wc[5] + bc[1];
    o.z = h0 * Wc[2] + h1 * Wc[6] + bc[2];
    o.w = h0 * Wc[3] + h1 * Wc[7] + bc[3];
    *reinterpret_cast<float4*>(out + (size_t)node * 4) = o;
}

extern "C" void kernel_launch(void* const* d_in, const int* in_sizes, int n_in,
                              void* d_out, int out_size, void* d_ws, size_t ws_size,
                              hipStream_t stream) {
    const float* x  = (const float*)d_in[0];
    const int*  ei  = (const int*)d_in[1];
    const float* W1 = (const float*)d_in[2];
    const float* b1 = (const float*)d_in[3];
    const float* W2 = (const float*)d_in[4];
    const float* b2 = (const float*)d_in[5];
    const float* W3 = (const float*)d_in[6];
    const float* b3 = (const float*)d_in[7];
    const float* Wc = (const float*)d_in[8];
    const float* bc = (const float*)d_in[9];

    const int n = in_sizes[0] / 128;
    const int e = in_sizes[1] / 2;
    const int* src = ei;
    const int* dst = ei + e;

    const int ND  = (n + DT - 1) >> DTBITS;   // dst tiles (49)
    const int NW  = ND;                        // src tiles (49)
    const int NBK = ND * NW;                   // 2401 buckets
    const int G   = (e + CHUNK - 1) / CHUNK;   // 782 chunks

    const size_t MB = 1024 * 1024;
    char* ws = (char*)d_ws;
    float* dinv   = (float*)(ws + 0);
    float* hsA    = (float*)(ws + 1 * MB);           // n*4 floats (1.6 MB)
    float* hsB    = (float*)(ws + 3 * MB);           // n*4 floats
    int*   btot   = (int*)  (ws + 5 * MB);           // NBK ints
    int*   bstart = (int*)  (ws + 5 * MB + 64 * 1024);
    char*  region = ws + 6 * MB;                     // hb / partial (aliased)
    int*   hb     = (int*)region;                    // G*NBK ints (~7.5 MB)
    float* partial = (float*)region;                 // ND*NWG*8192 floats
    size_t hbBytes = (size_t)G * NBK * 4;

    // pick NWG (wgroups per dtile) to fit workspace; partial aliases hb
    int NWG = 10;
    while (NWG > 1) {
        size_t partBytes = (size_t)ND * NWG * (4 * DT) * 4;
        size_t regBytes = partBytes > hbBytes ? partBytes : hbBytes;
        if (6 * MB + regBytes + (size_t)e * 4 <= ws_size) break;
        NWG--;
    }
    size_t partBytes = (size_t)ND * NWG * (4 * DT) * 4;
    size_t regBytes = partBytes > hbBytes ? partBytes : hbBytes;
    int* packed = (int*)(ws + 6 * MB + regBytes);    // e ints (25.6 MB)

    float* out  = (float*)d_out;
    float* hout = out + (size_t)n * 4;

    // Build 2D-bucketed edge list (once; reused by deg + 3 layers)
    k_hist<<<G, 256, 0, stream>>>(src, dst, hb, NW, NBK, e);
    k_scanA<<<NBK, 256, 0, stream>>>(hb, btot, NBK, G);
    k_scanB<<<1, 512, 0, stream>>>(btot, bstart, NBK, e);
    k_part<<<G, 256, 0, stream>>>(src, dst, hb, bstart, packed, NW, NBK, e);

    // degree -> dinv (hb is dead now; partial region reusable)
    k_degt<<<ND * NWG, 256, 0, stream>>>(bstart, packed, (int*)partial, NW, NWG);
    k_dinvc<<<ND * 8, 256, 0, stream>>>((const int*)partial, dinv, n, NWG);

    // Layer 1 GEMV: hsA = (x @ W1) * dinv
    k_mm1<<<(n + 3) / 4, 256, 0, stream>>>(x, W1, dinv, hsA, n);

    // Layer 1: tiled aggregate + finalize (fused W2)
    k_tile4<<<ND * NWG, 256, 0, stream>>>(bstart, packed, hsA, partial, n, NW, NWG);
    k_comb4<4><<<ND * 8, 256, 0, stream>>>(partial, hsA, dinv, b1, W2, hsB, n, NWG);
    // Layer 2: tiled aggregate + finalize (fused W3)
    k_tile4<<<ND * NWG, 256, 0, stream>>>(bstart, packed, hsB, partial, n, NW, NWG);
    k_comb4<2><<<ND * 8, 256, 0, stream>>>(partial, hsB, dinv, b2, W3, hsA, n, NWG);
    // Layer 3: tiled aggregate + finalize (fused classifier)
    k_tile2<<<ND * NWG, 256, 0, stream>>>(bstart, packed, hsA, partial, n, NW, NWG);
    k_comb3<<<ND * 8, 256, 0, stream>>>(partial, hsA, dinv, b3, Wc, bc, out, hout, n, NWG);

    (void)n_in; (void)out_size; (void)ws_size;
}

// Round 8
// 294.796 us; speedup vs baseline: 2.0300x; 2.0300x over previous
//
#include <hip/hip_runtime.h>
#include <math.h>

// GCN forward: 3x GCNConv (128->4->4->2) + classifier (2->4).
// Build a full per-node CSR (edges grouped by dst) with ZERO global atomics:
//   chunk-hist (128-node buckets) -> parallel scans -> partition ->
//   per-bucket LDS counting-sort (k_build: also emits degree->dinv + rowoff).
// Aggregation = owner-computes gather: one wave per node, coalesced row read,
// one divergent hs gather per edge, register shfl-reduce, NO atomics
// (r4-r7 showed LDS f32 atomic passes stuck at ~146us/pass; r2's atomic-free
// gather passes ran ~60-70us).

#define CHUNK 8192
#define MAXNB 1024     // level-1 bins (128-node buckets); n <= 131071
#define CAP   12288    // max edges staged per bucket (avg 8184, sigma~90)

// Chunk histogram over 128-node dst buckets, transposed store hbT[b][g].
__global__ void k_hist(const int* __restrict__ dst, int* __restrict__ hbT,
                       int NB, int G, int e) {
    __shared__ int hist[MAXNB];
    int g = blockIdx.x;
    for (int b = threadIdx.x; b < NB; b += 256) hist[b] = 0;
    __syncthreads();
    int i0 = g * CHUNK, i1 = min(i0 + CHUNK, e);
    for (int i = i0 + threadIdx.x; i < i1; i += 256)
        atomicAdd(&hist[dst[i] >> 7], 1);
    __syncthreads();
    for (int b = threadIdx.x; b < NB; b += 256)
        hbT[(size_t)b * G + g] = hist[b];
}

// Per-bucket exclusive scan over chunks (block per bucket, contiguous row).
__global__ void k_scanA(int* __restrict__ hbT, int* __restrict__ btot, int G) {
    __shared__ int part[256];
    int b = blockIdx.x, t = threadIdx.x;
    int* row = hbT + (size_t)b * G;
    int C = (G + 255) / 256;
    int lo = t * C, hi = min(lo + C, G);
    int s = 0;
    for (int i = lo; i < hi; i++) s += row[i];
    part[t] = s;
    __syncthreads();
#pragma unroll
    for (int off = 1; off < 256; off <<= 1) {
        int u = (t >= off) ? part[t - off] : 0;
        __syncthreads();
        part[t] += u;
        __syncthreads();
    }
    int run = part[t] - s;
    for (int i = lo; i < hi; i++) {
        int v = row[i];
        row[i] = run;
        run += v;
    }
    if (t == 255) btot[b] = part[255];
}

// Exclusive scan of NB bucket totals -> bstart.
__global__ void k_scanB(const int* __restrict__ btot, int* __restrict__ bstart,
                        int NB, int e) {
    __shared__ int part[512];
    int t = threadIdx.x;
    int C = (NB + 511) / 512;
    int lo = t * C, hi = min(lo + C, NB);
    int s = 0;
    for (int i = lo; i < hi; i++) s += btot[i];
    part[t] = s;
    __syncthreads();
#pragma unroll
    for (int off = 1; off < 512; off <<= 1) {
        int u = (t >= off) ? part[t - off] : 0;
        __syncthreads();
        part[t] += u;
        __syncthreads();
    }
    int run = part[t] - s;
    for (int i = lo; i < hi; i++) {
        bstart[i] = run;
        run += btot[i];
    }
    if (t == 511) bstart[NB] = e;
}

// Partition edges into 128-node dst buckets. packed = (dst&127)<<17 | src.
__global__ void k_part(const int* __restrict__ src, const int* __restrict__ dst,
                       const int* __restrict__ hbT, const int* __restrict__ bstart,
                       int* __restrict__ packed, int NB, int G, int e) {
    __shared__ int cur[MAXNB];
    int g = blockIdx.x;
    for (int b = threadIdx.x; b < NB; b += 256)
        cur[b] = hbT[(size_t)b * G + g] + bstart[b];
    __syncthreads();
    int i0 = g * CHUNK, i1 = min(i0 + CHUNK, e);
    for (int i = i0 + threadIdx.x; i < i1; i += 256) {
        int d = dst[i], s = src[i];
        int pos = atomicAdd(&cur[d >> 7], 1);
        packed[pos] = ((d & 127) << 17) | s;
    }
}

// Per-bucket counting sort (in place): stage bucket in LDS, histogram 128
// dst-locals, scan, emit dinv + rowoff, permute srcs back to per-node runs.
__global__ void k_build(const int* __restrict__ bstart, int* __restrict__ packed,
                        float* __restrict__ dinv, int* __restrict__ rowoff, int n) {
    __shared__ int stage[CAP];
    __shared__ int cnt[128];
    __shared__ int off[128];
    __shared__ int cur[128];
    int b = blockIdx.x, tid = threadIdx.x;
    int lo = bstart[b];
    int len = bstart[b + 1] - lo;
    if (len > CAP) len = CAP;  // safety clamp (len ~ Poisson(8184); never hit)
    if (tid < 128) cnt[tid] = 0;
    for (int i = tid; i < len; i += 256) stage[i] = packed[lo + i];
    __syncthreads();
    for (int i = tid; i < len; i += 256) atomicAdd(&cnt[stage[i] >> 17], 1);
    __syncthreads();
    if (tid < 128) off[tid] = cnt[tid];
    __syncthreads();
#pragma unroll
    for (int s = 1; s < 128; s <<= 1) {
        int v = 0;
        if (tid < 128 && tid >= s) v = off[tid - s];
        __syncthreads();
        if (tid < 128 && tid >= s) off[tid] += v;
        __syncthreads();
    }
    if (tid < 128) {
        int excl = off[tid] - cnt[tid];   // exclusive prefix
        int node = (b << 7) + tid;
        if (node < n) dinv[node] = 1.0f / sqrtf((float)(cnt[tid] + 1));
        if (node <= n) rowoff[node] = lo + excl;
        cur[tid] = excl;
    }
    __syncthreads();
    for (int i = tid; i < len; i += 256) {
        int w = stage[i];
        int p = atomicAdd(&cur[w >> 17], 1);
        packed[lo + p] = w & 0x1FFFF;     // store bare src; dst implicit by run
    }
}

// Layer 1 GEMV: one wave per node. hs = (x @ W1) * dinv.
__global__ void k_mm1(const float* __restrict__ x, const float* __restrict__ W,
                      const float* __restrict__ dinv, float* __restrict__ hs, int n) {
    int gid = blockIdx.x * blockDim.x + threadIdx.x;
    int node = gid >> 6;
    int lane = threadIdx.x & 63;
    if (node >= n) return;
    const float2 xv = *reinterpret_cast<const float2*>(x + (size_t)node * 128 + lane * 2);
    const float4 w0 = *reinterpret_cast<const float4*>(W + (lane * 2) * 4);
    const float4 w1 = *reinterpret_cast<const float4*>(W + (lane * 2 + 1) * 4);
    float a0 = xv.x * w0.x + xv.y * w1.x;
    float a1 = xv.x * w0.y + xv.y * w1.y;
    float a2 = xv.x * w0.z + xv.y * w1.z;
    float a3 = xv.x * w0.w + xv.y * w1.w;
#pragma unroll
    for (int m = 32; m >= 1; m >>= 1) {
        a0 += __shfl_xor(a0, m);
        a1 += __shfl_xor(a1, m);
        a2 += __shfl_xor(a2, m);
        a3 += __shfl_xor(a3, m);
    }
    if (lane == 0) {
        float di = dinv[node];
        *reinterpret_cast<float4*>(hs + (size_t)node * 4) =
            make_float4(a0 * di, a1 * di, a2 * di, a3 * di);
    }
}

// Gather + finalize, 4-wide hs. One wave per node, coalesced row read,
// divergent hs gather, register butterfly reduce. No atomics.
template <int FOUT>
__global__ void k_gath_fin4(const int* __restrict__ rowoff, const int* __restrict__ csr,
                            const float* __restrict__ hs, const float* __restrict__ dinv,
                            const float* __restrict__ b, const float* __restrict__ Wn,
                            float* __restrict__ hsn, int n) {
    int gid = blockIdx.x * blockDim.x + threadIdx.x;
    int node = gid >> 6;
    int lane = threadIdx.x & 63;
    if (node >= n) return;
    int start = rowoff[node], end = rowoff[node + 1];
    float a0 = 0.f, a1 = 0.f, a2 = 0.f, a3 = 0.f;
    for (int j = start + lane; j < end; j += 64) {
        int s = csr[j];
        float4 v = *reinterpret_cast<const float4*>(hs + (size_t)s * 4);
        a0 += v.x; a1 += v.y; a2 += v.z; a3 += v.w;
    }
#pragma unroll
    for (int m = 32; m >= 1; m >>= 1) {
        a0 += __shfl_xor(a0, m);
        a1 += __shfl_xor(a1, m);
        a2 += __shfl_xor(a2, m);
        a3 += __shfl_xor(a3, m);
    }
    if (lane == 0) {
        float4 s = *reinterpret_cast<const float4*>(hs + (size_t)node * 4);
        float di = dinv[node];
        float h0 = tanhf((a0 + s.x) * di + b[0]);
        float h1 = tanhf((a1 + s.y) * di + b[1]);
        float h2 = tanhf((a2 + s.z) * di + b[2]);
        float h3 = tanhf((a3 + s.w) * di + b[3]);
        float o[FOUT];
#pragma unroll
        for (int j = 0; j < FOUT; j++) {
            o[j] = (h0 * Wn[0 * FOUT + j] + h1 * Wn[1 * FOUT + j] +
                    h2 * Wn[2 * FOUT + j] + h3 * Wn[3 * FOUT + j]) * di;
        }
        if constexpr (FOUT == 4) {
            *reinterpret_cast<float4*>(hsn + (size_t)node * 4) =
                make_float4(o[0], o[1], o[2], o[3]);
        } else {
            *reinterpret_cast<float2*>(hsn + (size_t)node * 2) = make_float2(o[0], o[1]);
        }
    }
}

// Final layer: gather float2, h3 = tanh(...) -> hout; out = h3@Wc + bc.
__global__ void k_gath_fin3(const int* __restrict__ rowoff, const int* __restrict__ csr,
                            const float* __restrict__ hs, const float* __restrict__ dinv,
                            const float* __restrict__ b3, const float* __restrict__ Wc,
                            const float* __restrict__ bc, float* __restrict__ out,
                            float* __restrict__ hout, int n) {
    int gid = blockIdx.x * blockDim.x + threadIdx.x;
    int node = gid >> 6;
    int lane = threadIdx.x & 63;
    if (node >= n) return;
    int start = rowoff[node], end = rowoff[node + 1];
    float a0 = 0.f, a1 = 0.f;
    for (int j = start + lane; j < end; j += 64) {
        int s = csr[j];
        float2 v = *reinterpret_cast<const float2*>(hs + (size_t)s * 2);
        a0 += v.x; a1 += v.y;
    }
#pragma unroll
    for (int m = 32; m >= 1; m >>= 1) {
        a0 += __shfl_xor(a0, m);
        a1 += __shfl_xor(a1, m);
    }
    if (lane == 0) {
        float2 s = *reinterpret_cast<const float2*>(hs + (size_t)node * 2);
        float di = dinv[node];
        float h0 = tanhf((a0 + s.x) * di + b3[0]);
        float h1 = tanhf((a1 + s.y) * di + b3[1]);
        *reinterpret_cast<float2*>(hout + (size_t)node * 2) = make_float2(h0, h1);
        float4 o;
        o.x = h0 * Wc[0] + h1 * Wc[4] + bc[0];
        o.y = h0 * Wc[1] + h1 * Wc[5] + bc[1];
        o.z = h0 * Wc[2] + h1 * Wc[6] + bc[2];
        o.w = h0 * Wc[3] + h1 * Wc[7] + bc[3];
        *reinterpret_cast<float4*>(out + (size_t)node * 4) = o;
    }
}

extern "C" void kernel_launch(void* const* d_in, const int* in_sizes, int n_in,
                              void* d_out, int out_size, void* d_ws, size_t ws_size,
                              hipStream_t stream) {
    const float* x  = (const float*)d_in[0];
    const int*  ei  = (const int*)d_in[1];
    const float* W1 = (const float*)d_in[2];
    const float* b1 = (const float*)d_in[3];
    const float* W2 = (const float*)d_in[4];
    const float* b2 = (const float*)d_in[5];
    const float* W3 = (const float*)d_in[6];
    const float* b3 = (const float*)d_in[7];
    const float* Wc = (const float*)d_in[8];
    const float* bc = (const float*)d_in[9];

    const int n = in_sizes[0] / 128;
    const int e = in_sizes[1] / 2;
    const int* src = ei;
    const int* dst = ei + e;

    const int NB = (n + 127) >> 7;            // 128-node dst buckets (782)
    const int G  = (e + CHUNK - 1) / CHUNK;   // edge chunks (782)

    const size_t MB = 1024 * 1024;
    char* ws = (char*)d_ws;
    float* dinv   = (float*)(ws + 0);                 // n floats
    float* hsA    = (float*)(ws + MB / 2);            // n*4 floats (1.6 MB)
    float* hsB    = (float*)(ws + 2 * MB + MB / 2);   // n*4 floats
    int*   rowoff = (int*)  (ws + 4 * MB + MB / 2);   // n+1 ints
    int*   btot   = (int*)  (ws + 5 * MB);            // NB ints
    int*   bstart = (int*)  (ws + 5 * MB + 16 * 1024);
    int*   hbT    = (int*)  (ws + 5 * MB + MB / 2);   // NB*G ints (~2.45 MB)
    int*   packed = (int*)  (ws + 8 * MB + MB / 2);   // e ints (25.6 MB)

    float* out  = (float*)d_out;
    float* hout = out + (size_t)n * 4;

    // CSR build, zero global atomics
    k_hist<<<G, 256, 0, stream>>>(dst, hbT, NB, G, e);
    k_scanA<<<NB, 256, 0, stream>>>(hbT, btot, G);
    k_scanB<<<1, 512, 0, stream>>>(btot, bstart, NB, e);
    k_part<<<G, 256, 0, stream>>>(src, dst, hbT, bstart, packed, NB, G, e);
    k_build<<<NB, 256, 0, stream>>>(bstart, packed, dinv, rowoff, n);

    // Layer 1 GEMV: hsA = (x @ W1) * dinv
    const int wb = (n + 3) / 4;
    k_mm1<<<wb, 256, 0, stream>>>(x, W1, dinv, hsA, n);

    // Layers 1..3: owner-computes gather + fused finalize
    k_gath_fin4<4><<<wb, 256, 0, stream>>>(rowoff, packed, hsA, dinv, b1, W2, hsB, n);
    k_gath_fin4<2><<<wb, 256, 0, stream>>>(rowoff, packed, hsB, dinv, b2, W3, hsA, n);
    k_gath_fin3<<<wb, 256, 0, stream>>>(rowoff, packed, hsA, dinv, b3, Wc, bc, out, hout, n);

    (void)n_in; (void)out_size; (void)ws_size;
}

// Round 9
// 271.964 us; speedup vs baseline: 2.2005x; 1.0840x over previous
//
#include <hip/hip_runtime.h>
#include <math.h>

// GCN forward: 3x GCNConv (128->4->4->2) + classifier (2->4).
// CSR build with ZERO global atomics: chunk-hist (128-node dst buckets) ->
// parallel scans -> partition (long runs: CHUNK=16000 -> ~84B/run, XCD-
// contiguous chunk swizzle) -> per-bucket LDS counting-sort (k_build, also
// emits dinv + rowoff). Aggregation = owner-computes gather: one wave per
// node, coalesced row read, divergent hs gather, register shfl-reduce.
// (r8 evidence: atomic-free gathers fast; k_part write-amp 6.4x was leader.)

#define CHUNK 16000
#define MAXNB 1024     // 128-node buckets; n <= 131071
#define CAP   12288    // max edges staged per bucket (avg 8184, sigma~90)

// XCD-contiguous chunk assignment (bijective when G%8==0, else identity).
__device__ __forceinline__ int swz_chunk(int bid, int G) {
    if ((G & 7) != 0) return bid;
    return (bid & 7) * (G >> 3) + (bid >> 3);
}

// Chunk histogram over 128-node dst buckets, transposed store hbT[b][g].
__global__ void k_hist(const int* __restrict__ dst, int* __restrict__ hbT,
                       int NB, int G, int e) {
    __shared__ int hist[MAXNB];
    int g = swz_chunk(blockIdx.x, G);
    for (int b = threadIdx.x; b < NB; b += 512) hist[b] = 0;
    __syncthreads();
    long long i0 = (long long)g * CHUNK;
    int i1 = (int)min(i0 + CHUNK, (long long)e);
    for (int i = (int)i0 + threadIdx.x; i < i1; i += 512)
        atomicAdd(&hist[dst[i] >> 7], 1);
    __syncthreads();
    for (int b = threadIdx.x; b < NB; b += 512)
        hbT[(size_t)b * G + g] = hist[b];
}

// Per-bucket exclusive scan over chunks (block per bucket, contiguous row).
__global__ void k_scanA(int* __restrict__ hbT, int* __restrict__ btot, int G) {
    __shared__ int part[256];
    int b = blockIdx.x, t = threadIdx.x;
    int* row = hbT + (size_t)b * G;
    int C = (G + 255) / 256;
    int lo = t * C, hi = min(lo + C, G);
    int s = 0;
    for (int i = lo; i < hi; i++) s += row[i];
    part[t] = s;
    __syncthreads();
#pragma unroll
    for (int off = 1; off < 256; off <<= 1) {
        int u = (t >= off) ? part[t - off] : 0;
        __syncthreads();
        part[t] += u;
        __syncthreads();
    }
    int run = part[t] - s;
    for (int i = lo; i < hi; i++) {
        int v = row[i];
        row[i] = run;
        run += v;
    }
    if (t == 255) btot[b] = part[255];
}

// Exclusive scan of NB bucket totals -> bstart.
__global__ void k_scanB(const int* __restrict__ btot, int* __restrict__ bstart,
                        int NB, int e) {
    __shared__ int part[512];
    int t = threadIdx.x;
    int C = (NB + 511) / 512;
    int lo = t * C, hi = min(lo + C, NB);
    int s = 0;
    for (int i = lo; i < hi; i++) s += btot[i];
    part[t] = s;
    __syncthreads();
#pragma unroll
    for (int off = 1; off < 512; off <<= 1) {
        int u = (t >= off) ? part[t - off] : 0;
        __syncthreads();
        part[t] += u;
        __syncthreads();
    }
    int run = part[t] - s;
    for (int i = lo; i < hi; i++) {
        bstart[i] = run;
        run += btot[i];
    }
    if (t == 511) bstart[NB] = e;
}

// Partition edges into 128-node dst buckets. packed = (dst&127)<<17 | src.
__global__ void k_part(const int* __restrict__ src, const int* __restrict__ dst,
                       const int* __restrict__ hbT, const int* __restrict__ bstart,
                       int* __restrict__ packed, int NB, int G, int e) {
    __shared__ int cur[MAXNB];
    int g = swz_chunk(blockIdx.x, G);
    for (int b = threadIdx.x; b < NB; b += 512)
        cur[b] = hbT[(size_t)b * G + g] + bstart[b];
    __syncthreads();
    long long i0 = (long long)g * CHUNK;
    int i1 = (int)min(i0 + CHUNK, (long long)e);
    for (int i = (int)i0 + threadIdx.x; i < i1; i += 512) {
        int d = dst[i], s = src[i];
        int pos = atomicAdd(&cur[d >> 7], 1);
        packed[pos] = ((d & 127) << 17) | s;
    }
}

// Per-bucket counting sort (in place): stage bucket in LDS, histogram 128
// dst-locals, scan, emit dinv + rowoff, permute srcs back to per-node runs.
__global__ void k_build(const int* __restrict__ bstart, int* __restrict__ packed,
                        float* __restrict__ dinv, int* __restrict__ rowoff, int n) {
    __shared__ int stage[CAP];
    __shared__ int cnt[128];
    __shared__ int off[128];
    __shared__ int cur[128];
    int b = blockIdx.x, tid = threadIdx.x;
    int lo = bstart[b];
    int len = bstart[b + 1] - lo;
    if (len > CAP) len = CAP;  // safety clamp (len ~ Poisson(8184); never hit)
    if (tid < 128) cnt[tid] = 0;
    for (int i = tid; i < len; i += 256) stage[i] = packed[lo + i];
    __syncthreads();
    for (int i = tid; i < len; i += 256) atomicAdd(&cnt[stage[i] >> 17], 1);
    __syncthreads();
    if (tid < 128) off[tid] = cnt[tid];
    __syncthreads();
#pragma unroll
    for (int s = 1; s < 128; s <<= 1) {
        int v = 0;
        if (tid < 128 && tid >= s) v = off[tid - s];
        __syncthreads();
        if (tid < 128 && tid >= s) off[tid] += v;
        __syncthreads();
    }
    if (tid < 128) {
        int excl = off[tid] - cnt[tid];   // exclusive prefix
        int node = (b << 7) + tid;
        if (node < n) dinv[node] = 1.0f / sqrtf((float)(cnt[tid] + 1));
        if (node <= n) rowoff[node] = lo + excl;
        cur[tid] = excl;
    }
    __syncthreads();
    for (int i = tid; i < len; i += 256) {
        int w = stage[i];
        int p = atomicAdd(&cur[w >> 17], 1);
        packed[lo + p] = w & 0x1FFFF;     // store bare src; dst implicit by run
    }
}

// Layer 1 GEMV: one wave per node. hs = (x @ W1) * dinv.
__global__ void k_mm1(const float* __restrict__ x, const float* __restrict__ W,
                      const float* __restrict__ dinv, float* __restrict__ hs, int n) {
    int gid = blockIdx.x * blockDim.x + threadIdx.x;
    int node = gid >> 6;
    int lane = threadIdx.x & 63;
    if (node >= n) return;
    const float2 xv = *reinterpret_cast<const float2*>(x + (size_t)node * 128 + lane * 2);
    const float4 w0 = *reinterpret_cast<const float4*>(W + (lane * 2) * 4);
    const float4 w1 = *reinterpret_cast<const float4*>(W + (lane * 2 + 1) * 4);
    float a0 = xv.x * w0.x + xv.y * w1.x;
    float a1 = xv.x * w0.y + xv.y * w1.y;
    float a2 = xv.x * w0.z + xv.y * w1.z;
    float a3 = xv.x * w0.w + xv.y * w1.w;
#pragma unroll
    for (int m = 32; m >= 1; m >>= 1) {
        a0 += __shfl_xor(a0, m);
        a1 += __shfl_xor(a1, m);
        a2 += __shfl_xor(a2, m);
        a3 += __shfl_xor(a3, m);
    }
    if (lane == 0) {
        float di = dinv[node];
        *reinterpret_cast<float4*>(hs + (size_t)node * 4) =
            make_float4(a0 * di, a1 * di, a2 * di, a3 * di);
    }
}

// Gather + finalize, 4-wide hs. One wave per node, coalesced row read,
// divergent hs gather, register butterfly reduce. No atomics.
template <int FOUT>
__global__ void k_gath_fin4(const int* __restrict__ rowoff, const int* __restrict__ csr,
                            const float* __restrict__ hs, const float* __restrict__ dinv,
                            const float* __restrict__ b, const float* __restrict__ Wn,
                            float* __restrict__ hsn, int n) {
    int gid = blockIdx.x * blockDim.x + threadIdx.x;
    int node = gid >> 6;
    int lane = threadIdx.x & 63;
    if (node >= n) return;
    int start = rowoff[node], end = rowoff[node + 1];
    float a0 = 0.f, a1 = 0.f, a2 = 0.f, a3 = 0.f;
    for (int j = start + lane; j < end; j += 64) {
        int s = csr[j];
        float4 v = *reinterpret_cast<const float4*>(hs + (size_t)s * 4);
        a0 += v.x; a1 += v.y; a2 += v.z; a3 += v.w;
    }
#pragma unroll
    for (int m = 32; m >= 1; m >>= 1) {
        a0 += __shfl_xor(a0, m);
        a1 += __shfl_xor(a1, m);
        a2 += __shfl_xor(a2, m);
        a3 += __shfl_xor(a3, m);
    }
    if (lane == 0) {
        float4 s = *reinterpret_cast<const float4*>(hs + (size_t)node * 4);
        float di = dinv[node];
        float h0 = tanhf((a0 + s.x) * di + b[0]);
        float h1 = tanhf((a1 + s.y) * di + b[1]);
        float h2 = tanhf((a2 + s.z) * di + b[2]);
        float h3 = tanhf((a3 + s.w) * di + b[3]);
        float o[FOUT];
#pragma unroll
        for (int j = 0; j < FOUT; j++) {
            o[j] = (h0 * Wn[0 * FOUT + j] + h1 * Wn[1 * FOUT + j] +
                    h2 * Wn[2 * FOUT + j] + h3 * Wn[3 * FOUT + j]) * di;
        }
        if constexpr (FOUT == 4) {
            *reinterpret_cast<float4*>(hsn + (size_t)node * 4) =
                make_float4(o[0], o[1], o[2], o[3]);
        } else {
            *reinterpret_cast<float2*>(hsn + (size_t)node * 2) = make_float2(o[0], o[1]);
        }
    }
}

// Final layer: gather float2, h3 = tanh(...) -> hout; out = h3@Wc + bc.
__global__ void k_gath_fin3(const int* __restrict__ rowoff, const int* __restrict__ csr,
                            const float* __restrict__ hs, const float* __restrict__ dinv,
                            const float* __restrict__ b3, const float* __restrict__ Wc,
                            const float* __restrict__ bc, float* __restrict__ out,
                            float* __restrict__ hout, int n) {
    int gid = blockIdx.x * blockDim.x + threadIdx.x;
    int node = gid >> 6;
    int lane = threadIdx.x & 63;
    if (node >= n) return;
    int start = rowoff[node], end = rowoff[node + 1];
    float a0 = 0.f, a1 = 0.f;
    for (int j = start + lane; j < end; j += 64) {
        int s = csr[j];
        float2 v = *reinterpret_cast<const float2*>(hs + (size_t)s * 2);
        a0 += v.x; a1 += v.y;
    }
#pragma unroll
    for (int m = 32; m >= 1; m >>= 1) {
        a0 += __shfl_xor(a0, m);
        a1 += __shfl_xor(a1, m);
    }
    if (lane == 0) {
        float2 s = *reinterpret_cast<const float2*>(hs + (size_t)node * 2);
        float di = dinv[node];
        float h0 = tanhf((a0 + s.x) * di + b3[0]);
        float h1 = tanhf((a1 + s.y) * di + b3[1]);
        *reinterpret_cast<float2*>(hout + (size_t)node * 2) = make_float2(h0, h1);
        float4 o;
        o.x = h0 * Wc[0] + h1 * Wc[4] + bc[0];
        o.y = h0 * Wc[1] + h1 * Wc[5] + bc[1];
        o.z = h0 * Wc[2] + h1 * Wc[6] + bc[2];
        o.w = h0 * Wc[3] + h1 * Wc[7] + bc[3];
        *reinterpret_cast<float4*>(out + (size_t)node * 4) = o;
    }
}

extern "C" void kernel_launch(void* const* d_in, const int* in_sizes, int n_in,
                              void* d_out, int out_size, void* d_ws, size_t ws_size,
                              hipStream_t stream) {
    const float* x  = (const float*)d_in[0];
    const int*  ei  = (const int*)d_in[1];
    const float* W1 = (const float*)d_in[2];
    const float* b1 = (const float*)d_in[3];
    const float* W2 = (const float*)d_in[4];
    const float* b2 = (const float*)d_in[5];
    const float* W3 = (const float*)d_in[6];
    const float* b3 = (const float*)d_in[7];
    const float* Wc = (const float*)d_in[8];
    const float* bc = (const float*)d_in[9];

    const int n = in_sizes[0] / 128;
    const int e = in_sizes[1] / 2;
    const int* src = ei;
    const int* dst = ei + e;

    const int NB = (n + 127) >> 7;            // 128-node dst buckets (782)
    const int G  = (e + CHUNK - 1) / CHUNK;   // edge chunks (400)

    const size_t MB = 1024 * 1024;
    char* ws = (char*)d_ws;
    float* dinv   = (float*)(ws + 0);                 // n floats
    float* hsA    = (float*)(ws + MB / 2);            // n*4 floats (1.6 MB)
    float* hsB    = (float*)(ws + 2 * MB + MB / 2);   // n*4 floats
    int*   rowoff = (int*)  (ws + 4 * MB + MB / 2);   // n+1 ints
    int*   btot   = (int*)  (ws + 5 * MB);            // NB ints
    int*   bstart = (int*)  (ws + 5 * MB + 16 * 1024);
    int*   hbT    = (int*)  (ws + 5 * MB + MB / 2);   // NB*G ints (~1.25 MB)
    int*   packed = (int*)  (ws + 8 * MB + MB / 2);   // e ints (25.6 MB)

    float* out  = (float*)d_out;
    float* hout = out + (size_t)n * 4;

    // CSR build, zero global atomics
    k_hist<<<G, 512, 0, stream>>>(dst, hbT, NB, G, e);
    k_scanA<<<NB, 256, 0, stream>>>(hbT, btot, G);
    k_scanB<<<1, 512, 0, stream>>>(btot, bstart, NB, e);
    k_part<<<G, 512, 0, stream>>>(src, dst, hbT, bstart, packed, NB, G, e);
    k_build<<<NB, 256, 0, stream>>>(bstart, packed, dinv, rowoff, n);

    // Layer 1 GEMV: hsA = (x @ W1) * dinv
    const int wb = (n + 3) / 4;
    k_mm1<<<wb, 256, 0, stream>>>(x, W1, dinv, hsA, n);

    // Layers 1..3: owner-computes gather + fused finalize
    k_gath_fin4<4><<<wb, 256, 0, stream>>>(rowoff, packed, hsA, dinv, b1, W2, hsB, n);
    k_gath_fin4<2><<<wb, 256, 0, stream>>>(rowoff, packed, hsB, dinv, b2, W3, hsA, n);
    k_gath_fin3<<<wb, 256, 0, stream>>>(rowoff, packed, hsA, dinv, b3, Wc, bc, out, hout, n);

    (void)n_in; (void)out_size; (void)ws_size;
}